// Round 12
// baseline (456.024 us; speedup 1.0000x reference)
//
#include <hip/hip_runtime.h>

// ---------------------------------------------------------------------------
// GCN forward: 3x GCNConv(+relu) -> global_mean_pool -> fc -> log_softmax
// N=100000 nodes, E=3200000 edges, G=512 graphs, feats 128->64->128->64
// R11: agg v4 — quarter-wave per edge, unroll x8 (8 gathers in flight,
// 32 edges/iter = avg degree). CSR pairs packed to 4B (src | dlow<<23),
// halving binB write and bucketC read traffic.
// Operand pre-scaled bf16; layer 2 aggregate-first; LDS-binned radix build.
// ---------------------------------------------------------------------------

static inline int grid_for(long long total, int block) {
    return (int)((total + block - 1) / block);
}

#define NB_BIN 512    // binning blocks
#define BUK_SHIFT 9   // 512 nodes per bucket

__device__ __forceinline__ float bflo(unsigned int u) {
    union { unsigned int ui; float f; } c; c.ui = u << 16; return c.f;
}
__device__ __forceinline__ float bfhi(unsigned int u) {
    union { unsigned int ui; float f; } c; c.ui = u & 0xFFFF0000u; return c.f;
}
__device__ __forceinline__ unsigned short f2bf(float f) {
    union { unsigned int ui; float f; } c; c.f = f;
    unsigned int u = c.ui;
    return (unsigned short)((u + 0x7FFFu + ((u >> 16) & 1u)) >> 16);  // RNE
}

// --- pass A: per-(block,bucket) LDS histogram, transposed out --------------
__global__ __launch_bounds__(256) void k_histA(const int* __restrict__ dst,
                                               int* __restrict__ histT,
                                               int E, int nbuk) {
    __shared__ int h[256];
    const int c = blockIdx.x;
    for (int i = threadIdx.x; i < nbuk; i += 256) h[i] = 0;
    __syncthreads();
    const int per = (E + NB_BIN - 1) / NB_BIN;
    const int lo = c * per, hi = min(E, lo + per);
    for (int i = lo + (int)threadIdx.x; i < hi; i += 256)
        atomicAdd(&h[dst[i] >> BUK_SHIFT], 1);
    __syncthreads();
    for (int i = threadIdx.x; i < nbuk; i += 256)
        histT[i * NB_BIN + c] = h[i];
}

// --- linear 2-level scan ---------------------------------------------------
__global__ void k_scan_block_lin(const int* __restrict__ in, int* __restrict__ outI,
                                 int* __restrict__ partials, int M) {
    __shared__ int s[256];
    int tid = threadIdx.x;
    int i = blockIdx.x * 256 + tid;
    int v = (i < M) ? in[i] : 0;
    s[tid] = v;
    __syncthreads();
    for (int off = 1; off < 256; off <<= 1) {
        int t = (tid >= off) ? s[tid - off] : 0;
        __syncthreads();
        s[tid] += t;
        __syncthreads();
    }
    if (i < M) outI[i] = s[tid];  // block-inclusive
    if (tid == 255) partials[blockIdx.x] = s[255];
}

__global__ void k_scan_partials(int* __restrict__ partials, int nblk) {
    __shared__ int s[512];
    int tid = threadIdx.x;
    int v = (tid < nblk) ? partials[tid] : 0;
    s[tid] = v;
    __syncthreads();
    for (int off = 1; off < 512; off <<= 1) {
        int t = (tid >= off) ? s[tid - off] : 0;
        __syncthreads();
        s[tid] += t;
        __syncthreads();
    }
    if (tid < nblk) partials[tid] = s[tid] - v;  // exclusive
}

// --- pass B: bin packed (src | dlow<<23); per-block LDS cursors ------------
__global__ __launch_bounds__(256) void k_binB(const int* __restrict__ src,
                                              const int* __restrict__ dst,
                                              const int* __restrict__ histT,
                                              const int* __restrict__ scanI,
                                              const int* __restrict__ partials,
                                              unsigned int* __restrict__ pairs,
                                              int E, int nbuk) {
    __shared__ int cur[256];
    const int c = blockIdx.x;
    for (int b = threadIdx.x; b < nbuk; b += 256) {
        int idx = b * NB_BIN + c;
        cur[b] = scanI[idx] - histT[idx] + partials[idx >> 8];
    }
    __syncthreads();
    const int per = (E + NB_BIN - 1) / NB_BIN;
    const int lo = c * per, hi = min(E, lo + per);
    for (int i = lo + (int)threadIdx.x; i < hi; i += 256) {
        int d = dst[i];
        int pos = atomicAdd(&cur[d >> BUK_SHIFT], 1);
        pairs[pos] = (unsigned int)src[i] | ((unsigned int)(d & 511) << 23);
    }
}

// --- pass C: per-bucket counting sort + CSR metadata -----------------------
__global__ __launch_bounds__(256) void k_bucketC(const unsigned int* __restrict__ pairs,
                                                 const int* __restrict__ histT,
                                                 const int* __restrict__ scanI,
                                                 const int* __restrict__ partials,
                                                 int* __restrict__ srt,
                                                 int* __restrict__ counts,
                                                 int* __restrict__ rowoff,
                                                 float* __restrict__ dinv,
                                                 int E, int nbuk, int N) {
    const int b = blockIdx.x;
    const int tid = threadIdx.x;
    __shared__ int h[512];
    __shared__ int loff[512];
    __shared__ int s2[256];

    int idx0 = b * NB_BIN;
    int base = scanI[idx0] - histT[idx0] + partials[idx0 >> 8];
    int end;
    if (b + 1 < nbuk) {
        int idx1 = (b + 1) * NB_BIN;
        end = scanI[idx1] - histT[idx1] + partials[idx1 >> 8];
    } else {
        end = E;
    }

    const int n0 = b << BUK_SHIFT;
    const int nn = min(512, N - n0);

    h[tid] = 0; h[tid + 256] = 0;
    __syncthreads();
    for (int i = base + tid; i < end; i += 256)
        atomicAdd(&h[pairs[i] >> 23], 1);
    __syncthreads();

    int a0 = h[2 * tid], a1 = h[2 * tid + 1];
    s2[tid] = a0 + a1;
    __syncthreads();
    for (int off = 1; off < 256; off <<= 1) {
        int t = (tid >= off) ? s2[tid - off] : 0;
        __syncthreads();
        s2[tid] += t;
        __syncthreads();
    }
    int e2 = s2[tid] - (a0 + a1);
    loff[2 * tid] = e2;
    loff[2 * tid + 1] = e2 + a0;
    __syncthreads();

    for (int i = tid; i < nn; i += 256) {
        int cc = h[i];
        counts[n0 + i] = cc;
        rowoff[n0 + i] = base + loff[i];
        dinv[n0 + i] = rsqrtf((float)cc + 1.0f);
    }
    __syncthreads();
    h[tid] = loff[tid]; h[tid + 256] = loff[tid + 256];
    __syncthreads();
    for (int i = base + tid; i < end; i += 256) {
        unsigned int p = pairs[i];
        int pos = atomicAdd(&h[p >> 23], 1);
        srt[base + pos] = (int)(p & 0x7FFFFFu);
    }
}

// --- register-blocked tiled GEMM: H[N,OUT] = X[N,IN] @ W[IN,OUT] -----------
// BR: fuse relu(out+bias). OB: output bf16, pre-scaled by scale[row].
template <int IN, int OUT, int TN, bool BR, bool OB>
__global__ __launch_bounds__(256) void k_gemm_tile(const float* __restrict__ X,
                                                   const float* __restrict__ W,
                                                   const float* __restrict__ bias,
                                                   const float* __restrict__ scale,
                                                   void* __restrict__ Hv, int N) {
    constexpr int ROWS = 64;
    constexpr int CT = OUT / TN;
    constexpr int RT = 256 / CT;
    constexpr int TM = ROWS / RT;
    static_assert(CT * RT == 256 && TM * RT == ROWS, "tile mismatch");
    __shared__ float Xs[ROWS][IN];
    __shared__ float Ws[IN][OUT];

    const int tid = threadIdx.x;
    const int row0 = blockIdx.x * ROWS;

    for (int i = tid; i < IN * OUT / 4; i += 256)
        ((float4*)Ws)[i] = ((const float4*)W)[i];
    for (int i = tid; i < ROWS * IN / 4; i += 256) {
        int r = i / (IN / 4), kq = i % (IN / 4);
        float4 v = make_float4(0.f, 0.f, 0.f, 0.f);
        if (row0 + r < N) v = *(const float4*)(X + (size_t)(row0 + r) * IN + kq * 4);
        *(float4*)&Xs[r][kq * 4] = v;
    }
    __syncthreads();

    const int tx = tid % CT;
    const int ty = tid / CT;

    float acc[TM][TN];
#pragma unroll
    for (int m = 0; m < TM; ++m)
#pragma unroll
        for (int n = 0; n < TN; ++n) acc[m][n] = 0.0f;

#pragma unroll 2
    for (int kq = 0; kq < IN / 4; ++kq) {
        float a[TM][4];
#pragma unroll
        for (int m = 0; m < TM; ++m) {
            float4 t = *(const float4*)&Xs[ty * TM + m][kq * 4];
            a[m][0] = t.x; a[m][1] = t.y; a[m][2] = t.z; a[m][3] = t.w;
        }
#pragma unroll
        for (int j = 0; j < 4; ++j) {
            float b[TN];
#pragma unroll
            for (int n4 = 0; n4 < TN / 4; ++n4) {
                float4 t = *(const float4*)&Ws[kq * 4 + j][tx * TN + n4 * 4];
                b[n4 * 4 + 0] = t.x; b[n4 * 4 + 1] = t.y;
                b[n4 * 4 + 2] = t.z; b[n4 * 4 + 3] = t.w;
            }
#pragma unroll
            for (int m = 0; m < TM; ++m)
#pragma unroll
                for (int n = 0; n < TN; ++n)
                    acc[m][n] = fmaf(a[m][j], b[n], acc[m][n]);
        }
    }

#pragma unroll
    for (int m = 0; m < TM; ++m) {
        int r = row0 + ty * TM + m;
        if (r >= N) continue;
        float sc = OB ? scale[r] : 1.0f;
#pragma unroll
        for (int n4 = 0; n4 < TN / 4; ++n4) {
            float4 o = make_float4(acc[m][n4 * 4 + 0], acc[m][n4 * 4 + 1],
                                   acc[m][n4 * 4 + 2], acc[m][n4 * 4 + 3]);
            if (BR) {
                float4 b4 = *(const float4*)&bias[tx * TN + n4 * 4];
                o.x = fmaxf(o.x + b4.x, 0.0f);
                o.y = fmaxf(o.y + b4.y, 0.0f);
                o.z = fmaxf(o.z + b4.z, 0.0f);
                o.w = fmaxf(o.w + b4.w, 0.0f);
            }
            if (OB) {
                ushort4 o16;
                o16.x = f2bf(o.x * sc); o16.y = f2bf(o.y * sc);
                o16.z = f2bf(o.z * sc); o16.w = f2bf(o.w * sc);
                *(ushort4*)((unsigned short*)Hv + (size_t)r * OUT + tx * TN + n4 * 4) = o16;
            } else {
                *(float4*)((float*)Hv + (size_t)r * OUT + tx * TN + n4 * 4) = o;
            }
        }
    }
}

// --- aggregation v4: quarter-wave per edge, uint2 (4 bf16) per lane,
// unroll x8 (8 gathers in flight, 32 edges/iter).
// acc = dv * (Hs[node] + sum_e Hs[src_e]);  Hs pre-scaled by dinv.
// BR: relu(acc+bias). OB: bf16 out. PS: pre-scale output by dv.
template <bool BR, bool OB, bool PS>
__global__ void k_agg64_v4(const int* __restrict__ srt, const int* __restrict__ rowoff,
                           const int* __restrict__ counts, const float* __restrict__ dinv,
                           const uint2* __restrict__ Hs, const float* __restrict__ bias,
                           void* __restrict__ Ov, int N) {
    int node = blockIdx.x * (blockDim.x >> 6) + (threadIdx.x >> 6);
    int lane = threadIdx.x & 63;
    int q = lane >> 4, l4 = lane & 15;
    if (node >= N) return;
    float dv = dinv[node];
    const int* sp = srt + rowoff[node];
    int ce = counts[node];

    float a0 = 0.f, a1 = 0.f, a2 = 0.f, a3 = 0.f;
    if (q == 0) {  // self-loop once
        uint2 u = Hs[(size_t)node * 16 + l4];
        a0 = bflo(u.x); a1 = bfhi(u.x); a2 = bflo(u.y); a3 = bfhi(u.y);
    }
    int e = q;
    for (; e + 28 < ce; e += 32) {  // 8 gathers in flight per quarter
        int s0 = sp[e],      s1 = sp[e + 4],  s2 = sp[e + 8],  s3 = sp[e + 12];
        int s4 = sp[e + 16], s5 = sp[e + 20], s6 = sp[e + 24], s7 = sp[e + 28];
        uint2 u0 = Hs[(size_t)s0 * 16 + l4];
        uint2 u1 = Hs[(size_t)s1 * 16 + l4];
        uint2 u2 = Hs[(size_t)s2 * 16 + l4];
        uint2 u3 = Hs[(size_t)s3 * 16 + l4];
        uint2 u4 = Hs[(size_t)s4 * 16 + l4];
        uint2 u5 = Hs[(size_t)s5 * 16 + l4];
        uint2 u6 = Hs[(size_t)s6 * 16 + l4];
        uint2 u7 = Hs[(size_t)s7 * 16 + l4];
        a0 += bflo(u0.x); a1 += bfhi(u0.x); a2 += bflo(u0.y); a3 += bfhi(u0.y);
        a0 += bflo(u1.x); a1 += bfhi(u1.x); a2 += bflo(u1.y); a3 += bfhi(u1.y);
        a0 += bflo(u2.x); a1 += bfhi(u2.x); a2 += bflo(u2.y); a3 += bfhi(u2.y);
        a0 += bflo(u3.x); a1 += bfhi(u3.x); a2 += bflo(u3.y); a3 += bfhi(u3.y);
        a0 += bflo(u4.x); a1 += bfhi(u4.x); a2 += bflo(u4.y); a3 += bfhi(u4.y);
        a0 += bflo(u5.x); a1 += bfhi(u5.x); a2 += bflo(u5.y); a3 += bfhi(u5.y);
        a0 += bflo(u6.x); a1 += bfhi(u6.x); a2 += bflo(u6.y); a3 += bfhi(u6.y);
        a0 += bflo(u7.x); a1 += bfhi(u7.x); a2 += bflo(u7.y); a3 += bfhi(u7.y);
    }
    for (; e < ce; e += 4) {
        uint2 u = Hs[(size_t)sp[e] * 16 + l4];
        a0 += bflo(u.x); a1 += bfhi(u.x); a2 += bflo(u.y); a3 += bfhi(u.y);
    }
    a0 += __shfl_xor(a0, 16, 64); a0 += __shfl_xor(a0, 32, 64);
    a1 += __shfl_xor(a1, 16, 64); a1 += __shfl_xor(a1, 32, 64);
    a2 += __shfl_xor(a2, 16, 64); a2 += __shfl_xor(a2, 32, 64);
    a3 += __shfl_xor(a3, 16, 64); a3 += __shfl_xor(a3, 32, 64);

    float o0 = a0 * dv, o1 = a1 * dv, o2 = a2 * dv, o3 = a3 * dv;
    if (BR) {
        float4 b4 = *(const float4*)(bias + 4 * l4);
        o0 = fmaxf(o0 + b4.x, 0.0f);
        o1 = fmaxf(o1 + b4.y, 0.0f);
        o2 = fmaxf(o2 + b4.z, 0.0f);
        o3 = fmaxf(o3 + b4.w, 0.0f);
    }
    if (PS) { o0 *= dv; o1 *= dv; o2 *= dv; o3 *= dv; }
    if (q == 0) {
        if (OB) {
            uint2 o;
            o.x = (unsigned int)f2bf(o0) | ((unsigned int)f2bf(o1) << 16);
            o.y = (unsigned int)f2bf(o2) | ((unsigned int)f2bf(o3) << 16);
            ((uint2*)Ov)[(size_t)node * 16 + l4] = o;
        } else {
            ((float4*)Ov)[(size_t)node * 16 + l4] = make_float4(o0, o1, o2, o3);
        }
    }
}

// --- pooling (batch sorted): wave-run accumulation ------------------------
__global__ void k_zero_f(float* p, int n) {
    int i = blockIdx.x * blockDim.x + threadIdx.x;
    if (i < n) p[i] = 0.0f;
}

__global__ void k_pool_seg(const float* __restrict__ H, const int* __restrict__ batch,
                           float* __restrict__ sums, float* __restrict__ cnt, int N) {
    int gw = (blockIdx.x * blockDim.x + threadIdx.x) >> 6;
    int lane = threadIdx.x & 63;
    int start = gw * 64;
    if (start >= N) return;
    int end = min(N, start + 64);
    int gcur = batch[start];
    float acc = 0.0f, c = 0.0f;
    for (int i = start; i < end; ++i) {
        int g = batch[i];
        if (g != gcur) {
            atomicAdd(&sums[(size_t)gcur * 64 + lane], acc);
            if (lane == 0) atomicAdd(&cnt[gcur], c);
            acc = 0.0f; c = 0.0f; gcur = g;
        }
        acc += H[(size_t)i * 64 + lane];
        c += 1.0f;
    }
    atomicAdd(&sums[(size_t)gcur * 64 + lane], acc);
    if (lane == 0) atomicAdd(&cnt[gcur], c);
}

// --- head: mean, fc, log_softmax ------------------------------------------
__global__ void k_head(const float* __restrict__ sums, const float* __restrict__ cnt,
                       const float* __restrict__ fcw, const float* __restrict__ fcb,
                       float* __restrict__ out, int G) {
    int g = blockIdx.x * blockDim.x + threadIdx.x;
    if (g >= G) return;
    float inv = 1.0f / fmaxf(cnt[g], 1.0f);
    float l[6];
#pragma unroll
    for (int c = 0; c < 6; ++c) {
        float acc = fcb[c];
        for (int f = 0; f < 64; ++f)
            acc = fmaf(sums[(size_t)g * 64 + f] * inv, fcw[f * 6 + c], acc);
        l[c] = acc;
    }
    float m = l[0];
#pragma unroll
    for (int c = 1; c < 6; ++c) m = fmaxf(m, l[c]);
    float se = 0.0f;
#pragma unroll
    for (int c = 0; c < 6; ++c) se += expf(l[c] - m);
    float lse = m + logf(se);
#pragma unroll
    for (int c = 0; c < 6; ++c) out[(size_t)g * 6 + c] = l[c] - lse;
}

// ---------------------------------------------------------------------------
extern "C" void kernel_launch(void* const* d_in, const int* in_sizes, int n_in,
                              void* d_out, int out_size, void* d_ws, size_t ws_size,
                              hipStream_t stream) {
    const float* x    = (const float*)d_in[0];
    const int*   eidx = (const int*)d_in[1];
    const int*   batch= (const int*)d_in[2];
    const float* W1   = (const float*)d_in[3];
    const float* b1   = (const float*)d_in[4];
    const float* W2   = (const float*)d_in[5];
    const float* b2   = (const float*)d_in[6];
    const float* W3   = (const float*)d_in[7];
    const float* b3   = (const float*)d_in[8];
    const float* fcw  = (const float*)d_in[9];
    const float* fcb  = (const float*)d_in[10];
    float* out = (float*)d_out;

    const int N = in_sizes[2];          // 100000
    const int E = in_sizes[1] / 2;      // 3200000
    const int G = out_size / 6;         // 512
    const int nbuk = (N + 511) >> BUK_SHIFT;  // 196
    const int M = nbuk * NB_BIN;              // 100352

    const int* src = eidx;
    const int* dst = eidx + E;

    float* ws = (float*)d_ws;
    size_t off = 0;
    auto take = [&](size_t n4) {
        float* p = ws + off;
        off += (n4 + 15) & ~(size_t)15;
        return p;
    };
    float* dinv    = take((size_t)N);
    int*   srt     = (int*)take((size_t)E);
    int*   rowoff  = (int*)take((size_t)N);
    int*   counts  = (int*)take((size_t)N);
    int*   histT   = (int*)take((size_t)M);
    int*   scanI   = (int*)take((size_t)M);
    int*   partials= (int*)take(512);
    uint2* H16a    = (uint2*)take((size_t)N * 32);  // N*64 bf16
    uint2* H16b    = (uint2*)take((size_t)N * 32);  // N*64 bf16
    float* A32     = take((size_t)N * 64);
    float* B32     = take((size_t)N * 128);
    float* sums    = take((size_t)G * 64);
    float* cnt     = take((size_t)G);
    (void)ws_size;

    unsigned int* pairs = (unsigned int*)B32;  // alias: B32 dead until GEMM2

    const int B = 256;
    const int NBLK_M = grid_for(M, 256);  // 392

    // --- CSR build (LDS-binned two-level radix, packed pairs) ---
    k_histA<<<NB_BIN, B, 0, stream>>>(dst, histT, E, nbuk);
    k_scan_block_lin<<<NBLK_M, B, 0, stream>>>(histT, scanI, partials, M);
    k_scan_partials<<<1, 512, 0, stream>>>(partials, NBLK_M);
    k_binB<<<NB_BIN, B, 0, stream>>>(src, dst, histT, scanI, partials, pairs, E, nbuk);
    k_bucketC<<<nbuk, B, 0, stream>>>(pairs, histT, scanI, partials, srt, counts,
                                      rowoff, dinv, E, nbuk, N);

    // --- layer 1: H16a = (x@W1)*dinv (bf16); agg -> H16b (bf16, rescaled) ---
    k_gemm_tile<128, 64, 4, false, true><<<grid_for(N, 64), B, 0, stream>>>(x, W1, nullptr, dinv, H16a, N);
    k_agg64_v4<true, true, true><<<grid_for(N, 4), B, 0, stream>>>(srt, rowoff, counts, dinv, H16a, b1, H16b, N);

    // --- layer 2 (aggregate-first): A32 = A_norm-apply on H16b (fp32);
    //     B32 = relu(A32@W2 + b2) [N,128] ---
    k_agg64_v4<false, false, false><<<grid_for(N, 4), B, 0, stream>>>(srt, rowoff, counts, dinv, H16b, nullptr, A32, N);
    k_gemm_tile<64, 128, 8, true, false><<<grid_for(N, 64), B, 0, stream>>>(A32, W2, b2, nullptr, B32, N);

    // --- layer 3: H16a = (B32@W3)*dinv (bf16); agg -> A32 = relu(.+b3) fp32 ---
    k_gemm_tile<128, 64, 4, false, true><<<grid_for(N, 64), B, 0, stream>>>(B32, W3, nullptr, dinv, H16a, N);
    k_agg64_v4<true, false, false><<<grid_for(N, 4), B, 0, stream>>>(srt, rowoff, counts, dinv, H16a, b3, A32, N);

    // --- pool + head ---
    k_zero_f<<<grid_for(G * 64, B), B, 0, stream>>>(sums, G * 64);
    k_zero_f<<<grid_for(G, B), B, 0, stream>>>(cnt, G);
    k_pool_seg<<<grid_for((long long)grid_for(N, 64) * 64, B), B, 0, stream>>>(A32, batch, sums, cnt, N);
    k_head<<<grid_for(G, 64), 64, 0, stream>>>(sums, cnt, fcw, fcb, out, G);
}

// Round 13
// 408.136 us; speedup vs baseline: 1.1173x; 1.1173x over previous
//
#include <hip/hip_runtime.h>

// ---------------------------------------------------------------------------
// GCN forward: 3x GCNConv(+relu) -> global_mean_pool -> fc -> log_softmax
// N=100000 nodes, E=3200000 edges, G=512 graphs, feats 128->64->128->64
// R12: revert agg to v3 (quarter-wave, unroll x4 = 4 gathers in flight;
// R11's x8 regressed via tail dominance + occupancy). Add x2 tail stage.
// Keep packed 4B pairs in the radix build. Pre-scaled bf16 operand;
// layer 2 aggregate-first; LDS-binned two-level radix CSR build.
// ---------------------------------------------------------------------------

static inline int grid_for(long long total, int block) {
    return (int)((total + block - 1) / block);
}

#define NB_BIN 512    // binning blocks
#define BUK_SHIFT 9   // 512 nodes per bucket

__device__ __forceinline__ float bflo(unsigned int u) {
    union { unsigned int ui; float f; } c; c.ui = u << 16; return c.f;
}
__device__ __forceinline__ float bfhi(unsigned int u) {
    union { unsigned int ui; float f; } c; c.ui = u & 0xFFFF0000u; return c.f;
}
__device__ __forceinline__ unsigned short f2bf(float f) {
    union { unsigned int ui; float f; } c; c.f = f;
    unsigned int u = c.ui;
    return (unsigned short)((u + 0x7FFFu + ((u >> 16) & 1u)) >> 16);  // RNE
}

// --- pass A: per-(block,bucket) LDS histogram, transposed out --------------
__global__ __launch_bounds__(256) void k_histA(const int* __restrict__ dst,
                                               int* __restrict__ histT,
                                               int E, int nbuk) {
    __shared__ int h[256];
    const int c = blockIdx.x;
    for (int i = threadIdx.x; i < nbuk; i += 256) h[i] = 0;
    __syncthreads();
    const int per = (E + NB_BIN - 1) / NB_BIN;
    const int lo = c * per, hi = min(E, lo + per);
    for (int i = lo + (int)threadIdx.x; i < hi; i += 256)
        atomicAdd(&h[dst[i] >> BUK_SHIFT], 1);
    __syncthreads();
    for (int i = threadIdx.x; i < nbuk; i += 256)
        histT[i * NB_BIN + c] = h[i];
}

// --- linear 2-level scan ---------------------------------------------------
__global__ void k_scan_block_lin(const int* __restrict__ in, int* __restrict__ outI,
                                 int* __restrict__ partials, int M) {
    __shared__ int s[256];
    int tid = threadIdx.x;
    int i = blockIdx.x * 256 + tid;
    int v = (i < M) ? in[i] : 0;
    s[tid] = v;
    __syncthreads();
    for (int off = 1; off < 256; off <<= 1) {
        int t = (tid >= off) ? s[tid - off] : 0;
        __syncthreads();
        s[tid] += t;
        __syncthreads();
    }
    if (i < M) outI[i] = s[tid];  // block-inclusive
    if (tid == 255) partials[blockIdx.x] = s[255];
}

__global__ void k_scan_partials(int* __restrict__ partials, int nblk) {
    __shared__ int s[512];
    int tid = threadIdx.x;
    int v = (tid < nblk) ? partials[tid] : 0;
    s[tid] = v;
    __syncthreads();
    for (int off = 1; off < 512; off <<= 1) {
        int t = (tid >= off) ? s[tid - off] : 0;
        __syncthreads();
        s[tid] += t;
        __syncthreads();
    }
    if (tid < nblk) partials[tid] = s[tid] - v;  // exclusive
}

// --- pass B: bin packed (src | dlow<<23); per-block LDS cursors ------------
__global__ __launch_bounds__(256) void k_binB(const int* __restrict__ src,
                                              const int* __restrict__ dst,
                                              const int* __restrict__ histT,
                                              const int* __restrict__ scanI,
                                              const int* __restrict__ partials,
                                              unsigned int* __restrict__ pairs,
                                              int E, int nbuk) {
    __shared__ int cur[256];
    const int c = blockIdx.x;
    for (int b = threadIdx.x; b < nbuk; b += 256) {
        int idx = b * NB_BIN + c;
        cur[b] = scanI[idx] - histT[idx] + partials[idx >> 8];
    }
    __syncthreads();
    const int per = (E + NB_BIN - 1) / NB_BIN;
    const int lo = c * per, hi = min(E, lo + per);
    for (int i = lo + (int)threadIdx.x; i < hi; i += 256) {
        int d = dst[i];
        int pos = atomicAdd(&cur[d >> BUK_SHIFT], 1);
        pairs[pos] = (unsigned int)src[i] | ((unsigned int)(d & 511) << 23);
    }
}

// --- pass C: per-bucket counting sort + CSR metadata -----------------------
__global__ __launch_bounds__(256) void k_bucketC(const unsigned int* __restrict__ pairs,
                                                 const int* __restrict__ histT,
                                                 const int* __restrict__ scanI,
                                                 const int* __restrict__ partials,
                                                 int* __restrict__ srt,
                                                 int* __restrict__ counts,
                                                 int* __restrict__ rowoff,
                                                 float* __restrict__ dinv,
                                                 int E, int nbuk, int N) {
    const int b = blockIdx.x;
    const int tid = threadIdx.x;
    __shared__ int h[512];
    __shared__ int loff[512];
    __shared__ int s2[256];

    int idx0 = b * NB_BIN;
    int base = scanI[idx0] - histT[idx0] + partials[idx0 >> 8];
    int end;
    if (b + 1 < nbuk) {
        int idx1 = (b + 1) * NB_BIN;
        end = scanI[idx1] - histT[idx1] + partials[idx1 >> 8];
    } else {
        end = E;
    }

    const int n0 = b << BUK_SHIFT;
    const int nn = min(512, N - n0);

    h[tid] = 0; h[tid + 256] = 0;
    __syncthreads();
    for (int i = base + tid; i < end; i += 256)
        atomicAdd(&h[pairs[i] >> 23], 1);
    __syncthreads();

    int a0 = h[2 * tid], a1 = h[2 * tid + 1];
    s2[tid] = a0 + a1;
    __syncthreads();
    for (int off = 1; off < 256; off <<= 1) {
        int t = (tid >= off) ? s2[tid - off] : 0;
        __syncthreads();
        s2[tid] += t;
        __syncthreads();
    }
    int e2 = s2[tid] - (a0 + a1);
    loff[2 * tid] = e2;
    loff[2 * tid + 1] = e2 + a0;
    __syncthreads();

    for (int i = tid; i < nn; i += 256) {
        int cc = h[i];
        counts[n0 + i] = cc;
        rowoff[n0 + i] = base + loff[i];
        dinv[n0 + i] = rsqrtf((float)cc + 1.0f);
    }
    __syncthreads();
    h[tid] = loff[tid]; h[tid + 256] = loff[tid + 256];
    __syncthreads();
    for (int i = base + tid; i < end; i += 256) {
        unsigned int p = pairs[i];
        int pos = atomicAdd(&h[p >> 23], 1);
        srt[base + pos] = (int)(p & 0x7FFFFFu);
    }
}

// --- register-blocked tiled GEMM: H[N,OUT] = X[N,IN] @ W[IN,OUT] -----------
// BR: fuse relu(out+bias). OB: output bf16, pre-scaled by scale[row].
template <int IN, int OUT, int TN, bool BR, bool OB>
__global__ __launch_bounds__(256) void k_gemm_tile(const float* __restrict__ X,
                                                   const float* __restrict__ W,
                                                   const float* __restrict__ bias,
                                                   const float* __restrict__ scale,
                                                   void* __restrict__ Hv, int N) {
    constexpr int ROWS = 64;
    constexpr int CT = OUT / TN;
    constexpr int RT = 256 / CT;
    constexpr int TM = ROWS / RT;
    static_assert(CT * RT == 256 && TM * RT == ROWS, "tile mismatch");
    __shared__ float Xs[ROWS][IN];
    __shared__ float Ws[IN][OUT];

    const int tid = threadIdx.x;
    const int row0 = blockIdx.x * ROWS;

    for (int i = tid; i < IN * OUT / 4; i += 256)
        ((float4*)Ws)[i] = ((const float4*)W)[i];
    for (int i = tid; i < ROWS * IN / 4; i += 256) {
        int r = i / (IN / 4), kq = i % (IN / 4);
        float4 v = make_float4(0.f, 0.f, 0.f, 0.f);
        if (row0 + r < N) v = *(const float4*)(X + (size_t)(row0 + r) * IN + kq * 4);
        *(float4*)&Xs[r][kq * 4] = v;
    }
    __syncthreads();

    const int tx = tid % CT;
    const int ty = tid / CT;

    float acc[TM][TN];
#pragma unroll
    for (int m = 0; m < TM; ++m)
#pragma unroll
        for (int n = 0; n < TN; ++n) acc[m][n] = 0.0f;

#pragma unroll 2
    for (int kq = 0; kq < IN / 4; ++kq) {
        float a[TM][4];
#pragma unroll
        for (int m = 0; m < TM; ++m) {
            float4 t = *(const float4*)&Xs[ty * TM + m][kq * 4];
            a[m][0] = t.x; a[m][1] = t.y; a[m][2] = t.z; a[m][3] = t.w;
        }
#pragma unroll
        for (int j = 0; j < 4; ++j) {
            float b[TN];
#pragma unroll
            for (int n4 = 0; n4 < TN / 4; ++n4) {
                float4 t = *(const float4*)&Ws[kq * 4 + j][tx * TN + n4 * 4];
                b[n4 * 4 + 0] = t.x; b[n4 * 4 + 1] = t.y;
                b[n4 * 4 + 2] = t.z; b[n4 * 4 + 3] = t.w;
            }
#pragma unroll
            for (int m = 0; m < TM; ++m)
#pragma unroll
                for (int n = 0; n < TN; ++n)
                    acc[m][n] = fmaf(a[m][j], b[n], acc[m][n]);
        }
    }

#pragma unroll
    for (int m = 0; m < TM; ++m) {
        int r = row0 + ty * TM + m;
        if (r >= N) continue;
        float sc = OB ? scale[r] : 1.0f;
#pragma unroll
        for (int n4 = 0; n4 < TN / 4; ++n4) {
            float4 o = make_float4(acc[m][n4 * 4 + 0], acc[m][n4 * 4 + 1],
                                   acc[m][n4 * 4 + 2], acc[m][n4 * 4 + 3]);
            if (BR) {
                float4 b4 = *(const float4*)&bias[tx * TN + n4 * 4];
                o.x = fmaxf(o.x + b4.x, 0.0f);
                o.y = fmaxf(o.y + b4.y, 0.0f);
                o.z = fmaxf(o.z + b4.z, 0.0f);
                o.w = fmaxf(o.w + b4.w, 0.0f);
            }
            if (OB) {
                ushort4 o16;
                o16.x = f2bf(o.x * sc); o16.y = f2bf(o.y * sc);
                o16.z = f2bf(o.z * sc); o16.w = f2bf(o.w * sc);
                *(ushort4*)((unsigned short*)Hv + (size_t)r * OUT + tx * TN + n4 * 4) = o16;
            } else {
                *(float4*)((float*)Hv + (size_t)r * OUT + tx * TN + n4 * 4) = o;
            }
        }
    }
}

// --- aggregation v3b: quarter-wave per edge, uint2 (4 bf16) per lane,
// main loop x4 (4 gathers in flight), then x2 stage, then singles.
// acc = dv * (Hs[node] + sum_e Hs[src_e]);  Hs pre-scaled by dinv.
// BR: relu(acc+bias). OB: bf16 out. PS: pre-scale output by dv.
template <bool BR, bool OB, bool PS>
__global__ void k_agg64_v3b(const int* __restrict__ srt, const int* __restrict__ rowoff,
                            const int* __restrict__ counts, const float* __restrict__ dinv,
                            const uint2* __restrict__ Hs, const float* __restrict__ bias,
                            void* __restrict__ Ov, int N) {
    int node = blockIdx.x * (blockDim.x >> 6) + (threadIdx.x >> 6);
    int lane = threadIdx.x & 63;
    int q = lane >> 4, l4 = lane & 15;
    if (node >= N) return;
    float dv = dinv[node];
    const int* sp = srt + rowoff[node];
    int ce = counts[node];

    float a0 = 0.f, a1 = 0.f, a2 = 0.f, a3 = 0.f;
    if (q == 0) {  // self-loop once
        uint2 u = Hs[(size_t)node * 16 + l4];
        a0 = bflo(u.x); a1 = bfhi(u.x); a2 = bflo(u.y); a3 = bfhi(u.y);
    }
    int e = q;
    for (; e + 12 < ce; e += 16) {  // 4 gathers in flight per quarter
        int s0 = sp[e], s1 = sp[e + 4], s2 = sp[e + 8], s3 = sp[e + 12];
        uint2 u0 = Hs[(size_t)s0 * 16 + l4];
        uint2 u1 = Hs[(size_t)s1 * 16 + l4];
        uint2 u2 = Hs[(size_t)s2 * 16 + l4];
        uint2 u3 = Hs[(size_t)s3 * 16 + l4];
        a0 += bflo(u0.x); a1 += bfhi(u0.x); a2 += bflo(u0.y); a3 += bfhi(u0.y);
        a0 += bflo(u1.x); a1 += bfhi(u1.x); a2 += bflo(u1.y); a3 += bfhi(u1.y);
        a0 += bflo(u2.x); a1 += bfhi(u2.x); a2 += bflo(u2.y); a3 += bfhi(u2.y);
        a0 += bflo(u3.x); a1 += bfhi(u3.x); a2 += bflo(u3.y); a3 += bfhi(u3.y);
    }
    if (e + 4 < ce) {  // x2 stage (covers up to 8 remaining per quarter)
        int s0 = sp[e], s1 = sp[e + 4];
        uint2 u0 = Hs[(size_t)s0 * 16 + l4];
        uint2 u1 = Hs[(size_t)s1 * 16 + l4];
        a0 += bflo(u0.x); a1 += bfhi(u0.x); a2 += bflo(u0.y); a3 += bfhi(u0.y);
        a0 += bflo(u1.x); a1 += bfhi(u1.x); a2 += bflo(u1.y); a3 += bfhi(u1.y);
        e += 8;
    }
    if (e < ce) {
        uint2 u = Hs[(size_t)sp[e] * 16 + l4];
        a0 += bflo(u.x); a1 += bfhi(u.x); a2 += bflo(u.y); a3 += bfhi(u.y);
    }
    a0 += __shfl_xor(a0, 16, 64); a0 += __shfl_xor(a0, 32, 64);
    a1 += __shfl_xor(a1, 16, 64); a1 += __shfl_xor(a1, 32, 64);
    a2 += __shfl_xor(a2, 16, 64); a2 += __shfl_xor(a2, 32, 64);
    a3 += __shfl_xor(a3, 16, 64); a3 += __shfl_xor(a3, 32, 64);

    float o0 = a0 * dv, o1 = a1 * dv, o2 = a2 * dv, o3 = a3 * dv;
    if (BR) {
        float4 b4 = *(const float4*)(bias + 4 * l4);
        o0 = fmaxf(o0 + b4.x, 0.0f);
        o1 = fmaxf(o1 + b4.y, 0.0f);
        o2 = fmaxf(o2 + b4.z, 0.0f);
        o3 = fmaxf(o3 + b4.w, 0.0f);
    }
    if (PS) { o0 *= dv; o1 *= dv; o2 *= dv; o3 *= dv; }
    if (q == 0) {
        if (OB) {
            uint2 o;
            o.x = (unsigned int)f2bf(o0) | ((unsigned int)f2bf(o1) << 16);
            o.y = (unsigned int)f2bf(o2) | ((unsigned int)f2bf(o3) << 16);
            ((uint2*)Ov)[(size_t)node * 16 + l4] = o;
        } else {
            ((float4*)Ov)[(size_t)node * 16 + l4] = make_float4(o0, o1, o2, o3);
        }
    }
}

// --- pooling (batch sorted): wave-run accumulation ------------------------
__global__ void k_zero_f(float* p, int n) {
    int i = blockIdx.x * blockDim.x + threadIdx.x;
    if (i < n) p[i] = 0.0f;
}

__global__ void k_pool_seg(const float* __restrict__ H, const int* __restrict__ batch,
                           float* __restrict__ sums, float* __restrict__ cnt, int N) {
    int gw = (blockIdx.x * blockDim.x + threadIdx.x) >> 6;
    int lane = threadIdx.x & 63;
    int start = gw * 64;
    if (start >= N) return;
    int end = min(N, start + 64);
    int gcur = batch[start];
    float acc = 0.0f, c = 0.0f;
    for (int i = start; i < end; ++i) {
        int g = batch[i];
        if (g != gcur) {
            atomicAdd(&sums[(size_t)gcur * 64 + lane], acc);
            if (lane == 0) atomicAdd(&cnt[gcur], c);
            acc = 0.0f; c = 0.0f; gcur = g;
        }
        acc += H[(size_t)i * 64 + lane];
        c += 1.0f;
    }
    atomicAdd(&sums[(size_t)gcur * 64 + lane], acc);
    if (lane == 0) atomicAdd(&cnt[gcur], c);
}

// --- head: mean, fc, log_softmax ------------------------------------------
__global__ void k_head(const float* __restrict__ sums, const float* __restrict__ cnt,
                       const float* __restrict__ fcw, const float* __restrict__ fcb,
                       float* __restrict__ out, int G) {
    int g = blockIdx.x * blockDim.x + threadIdx.x;
    if (g >= G) return;
    float inv = 1.0f / fmaxf(cnt[g], 1.0f);
    float l[6];
#pragma unroll
    for (int c = 0; c < 6; ++c) {
        float acc = fcb[c];
        for (int f = 0; f < 64; ++f)
            acc = fmaf(sums[(size_t)g * 64 + f] * inv, fcw[f * 6 + c], acc);
        l[c] = acc;
    }
    float m = l[0];
#pragma unroll
    for (int c = 1; c < 6; ++c) m = fmaxf(m, l[c]);
    float se = 0.0f;
#pragma unroll
    for (int c = 0; c < 6; ++c) se += expf(l[c] - m);
    float lse = m + logf(se);
#pragma unroll
    for (int c = 0; c < 6; ++c) out[(size_t)g * 6 + c] = l[c] - lse;
}

// ---------------------------------------------------------------------------
extern "C" void kernel_launch(void* const* d_in, const int* in_sizes, int n_in,
                              void* d_out, int out_size, void* d_ws, size_t ws_size,
                              hipStream_t stream) {
    const float* x    = (const float*)d_in[0];
    const int*   eidx = (const int*)d_in[1];
    const int*   batch= (const int*)d_in[2];
    const float* W1   = (const float*)d_in[3];
    const float* b1   = (const float*)d_in[4];
    const float* W2   = (const float*)d_in[5];
    const float* b2   = (const float*)d_in[6];
    const float* W3   = (const float*)d_in[7];
    const float* b3   = (const float*)d_in[8];
    const float* fcw  = (const float*)d_in[9];
    const float* fcb  = (const float*)d_in[10];
    float* out = (float*)d_out;

    const int N = in_sizes[2];          // 100000
    const int E = in_sizes[1] / 2;      // 3200000
    const int G = out_size / 6;         // 512
    const int nbuk = (N + 511) >> BUK_SHIFT;  // 196
    const int M = nbuk * NB_BIN;              // 100352

    const int* src = eidx;
    const int* dst = eidx + E;

    float* ws = (float*)d_ws;
    size_t off = 0;
    auto take = [&](size_t n4) {
        float* p = ws + off;
        off += (n4 + 15) & ~(size_t)15;
        return p;
    };
    float* dinv    = take((size_t)N);
    int*   srt     = (int*)take((size_t)E);
    int*   rowoff  = (int*)take((size_t)N);
    int*   counts  = (int*)take((size_t)N);
    int*   histT   = (int*)take((size_t)M);
    int*   scanI   = (int*)take((size_t)M);
    int*   partials= (int*)take(512);
    uint2* H16a    = (uint2*)take((size_t)N * 32);  // N*64 bf16
    uint2* H16b    = (uint2*)take((size_t)N * 32);  // N*64 bf16
    float* A32     = take((size_t)N * 64);
    float* B32     = take((size_t)N * 128);
    float* sums    = take((size_t)G * 64);
    float* cnt     = take((size_t)G);
    (void)ws_size;

    unsigned int* pairs = (unsigned int*)B32;  // alias: B32 dead until GEMM2

    const int B = 256;
    const int NBLK_M = grid_for(M, 256);  // 392

    // --- CSR build (LDS-binned two-level radix, packed pairs) ---
    k_histA<<<NB_BIN, B, 0, stream>>>(dst, histT, E, nbuk);
    k_scan_block_lin<<<NBLK_M, B, 0, stream>>>(histT, scanI, partials, M);
    k_scan_partials<<<1, 512, 0, stream>>>(partials, NBLK_M);
    k_binB<<<NB_BIN, B, 0, stream>>>(src, dst, histT, scanI, partials, pairs, E, nbuk);
    k_bucketC<<<nbuk, B, 0, stream>>>(pairs, histT, scanI, partials, srt, counts,
                                      rowoff, dinv, E, nbuk, N);

    // --- layer 1: H16a = (x@W1)*dinv (bf16); agg -> H16b (bf16, rescaled) ---
    k_gemm_tile<128, 64, 4, false, true><<<grid_for(N, 64), B, 0, stream>>>(x, W1, nullptr, dinv, H16a, N);
    k_agg64_v3b<true, true, true><<<grid_for(N, 4), B, 0, stream>>>(srt, rowoff, counts, dinv, H16a, b1, H16b, N);

    // --- layer 2 (aggregate-first): A32 = A_norm-apply on H16b (fp32);
    //     B32 = relu(A32@W2 + b2) [N,128] ---
    k_agg64_v3b<false, false, false><<<grid_for(N, 4), B, 0, stream>>>(srt, rowoff, counts, dinv, H16b, nullptr, A32, N);
    k_gemm_tile<64, 128, 8, true, false><<<grid_for(N, 64), B, 0, stream>>>(A32, W2, b2, nullptr, B32, N);

    // --- layer 3: H16a = (B32@W3)*dinv (bf16); agg -> A32 = relu(.+b3) fp32 ---
    k_gemm_tile<128, 64, 4, false, true><<<grid_for(N, 64), B, 0, stream>>>(B32, W3, nullptr, dinv, H16a, N);
    k_agg64_v3b<true, false, false><<<grid_for(N, 4), B, 0, stream>>>(srt, rowoff, counts, dinv, H16a, b3, A32, N);

    // --- pool + head ---
    k_zero_f<<<grid_for(G * 64, B), B, 0, stream>>>(sums, G * 64);
    k_zero_f<<<grid_for(G, B), B, 0, stream>>>(cnt, G);
    k_pool_seg<<<grid_for((long long)grid_for(N, 64) * 64, B), B, 0, stream>>>(A32, batch, sums, cnt, N);
    k_head<<<grid_for(G, 64), 64, 0, stream>>>(sums, cnt, fcw, fcb, out, G);
}

// Round 14
// 397.475 us; speedup vs baseline: 1.1473x; 1.0268x over previous
//
#include <hip/hip_runtime.h>

// ---------------------------------------------------------------------------
// GCN forward: 3x GCNConv(+relu) -> global_mean_pool -> fc -> log_softmax
// N=100000 nodes, E=3200000 edges, G=512 graphs, feats 128->64->128->64
// R13: int4-vectorized edge reads in histA/binB (4 edges per instr);
// layer-2 aggregation output stored bf16 (GEMM2 stages bf16->f32 in LDS).
// Agg stays v3b (quarter-wave, x4 in flight + x2 tail — proven 62.7us,
// ~6.5 TB/s logical gather = line rate). LDS-binned radix CSR build.
// ---------------------------------------------------------------------------

static inline int grid_for(long long total, int block) {
    return (int)((total + block - 1) / block);
}

#define NB_BIN 512    // binning blocks
#define BUK_SHIFT 9   // 512 nodes per bucket

__device__ __forceinline__ float bflo(unsigned int u) {
    union { unsigned int ui; float f; } c; c.ui = u << 16; return c.f;
}
__device__ __forceinline__ float bfhi(unsigned int u) {
    union { unsigned int ui; float f; } c; c.ui = u & 0xFFFF0000u; return c.f;
}
__device__ __forceinline__ unsigned short f2bf(float f) {
    union { unsigned int ui; float f; } c; c.f = f;
    unsigned int u = c.ui;
    return (unsigned short)((u + 0x7FFFu + ((u >> 16) & 1u)) >> 16);  // RNE
}

// --- pass A: per-(block,bucket) LDS histogram (int4 reads), transposed out -
__global__ __launch_bounds__(256) void k_histA(const int* __restrict__ dst,
                                               int* __restrict__ histT,
                                               int E, int nbuk) {
    __shared__ int h[256];
    const int c = blockIdx.x;
    for (int i = threadIdx.x; i < nbuk; i += 256) h[i] = 0;
    __syncthreads();
    const int V4 = E >> 2;
    const int per = (V4 + NB_BIN - 1) / NB_BIN;
    const int lo = c * per, hi = min(V4, lo + per);
    for (int i4 = lo + (int)threadIdx.x; i4 < hi; i4 += 256) {
        int4 d4 = ((const int4*)dst)[i4];
        atomicAdd(&h[d4.x >> BUK_SHIFT], 1);
        atomicAdd(&h[d4.y >> BUK_SHIFT], 1);
        atomicAdd(&h[d4.z >> BUK_SHIFT], 1);
        atomicAdd(&h[d4.w >> BUK_SHIFT], 1);
    }
    if (c == 0 && threadIdx.x == 0) {  // scalar tail (E%4)
        for (int i = V4 << 2; i < E; ++i) atomicAdd(&h[dst[i] >> BUK_SHIFT], 1);
    }
    __syncthreads();
    for (int i = threadIdx.x; i < nbuk; i += 256)
        histT[i * NB_BIN + c] = h[i];
}

// --- linear 2-level scan ---------------------------------------------------
__global__ void k_scan_block_lin(const int* __restrict__ in, int* __restrict__ outI,
                                 int* __restrict__ partials, int M) {
    __shared__ int s[256];
    int tid = threadIdx.x;
    int i = blockIdx.x * 256 + tid;
    int v = (i < M) ? in[i] : 0;
    s[tid] = v;
    __syncthreads();
    for (int off = 1; off < 256; off <<= 1) {
        int t = (tid >= off) ? s[tid - off] : 0;
        __syncthreads();
        s[tid] += t;
        __syncthreads();
    }
    if (i < M) outI[i] = s[tid];  // block-inclusive
    if (tid == 255) partials[blockIdx.x] = s[255];
}

__global__ void k_scan_partials(int* __restrict__ partials, int nblk) {
    __shared__ int s[512];
    int tid = threadIdx.x;
    int v = (tid < nblk) ? partials[tid] : 0;
    s[tid] = v;
    __syncthreads();
    for (int off = 1; off < 512; off <<= 1) {
        int t = (tid >= off) ? s[tid - off] : 0;
        __syncthreads();
        s[tid] += t;
        __syncthreads();
    }
    if (tid < nblk) partials[tid] = s[tid] - v;  // exclusive
}

// --- pass B: bin packed (src | dlow<<23), int4 reads, LDS cursors ----------
__global__ __launch_bounds__(256) void k_binB(const int* __restrict__ src,
                                              const int* __restrict__ dst,
                                              const int* __restrict__ histT,
                                              const int* __restrict__ scanI,
                                              const int* __restrict__ partials,
                                              unsigned int* __restrict__ pairs,
                                              int E, int nbuk) {
    __shared__ int cur[256];
    const int c = blockIdx.x;
    for (int b = threadIdx.x; b < nbuk; b += 256) {
        int idx = b * NB_BIN + c;
        cur[b] = scanI[idx] - histT[idx] + partials[idx >> 8];
    }
    __syncthreads();
    const int V4 = E >> 2;
    const int per = (V4 + NB_BIN - 1) / NB_BIN;
    const int lo = c * per, hi = min(V4, lo + per);
    for (int i4 = lo + (int)threadIdx.x; i4 < hi; i4 += 256) {
        int4 d4 = ((const int4*)dst)[i4];
        int4 s4 = ((const int4*)src)[i4];
        int p0 = atomicAdd(&cur[d4.x >> BUK_SHIFT], 1);
        pairs[p0] = (unsigned int)s4.x | ((unsigned int)(d4.x & 511) << 23);
        int p1 = atomicAdd(&cur[d4.y >> BUK_SHIFT], 1);
        pairs[p1] = (unsigned int)s4.y | ((unsigned int)(d4.y & 511) << 23);
        int p2 = atomicAdd(&cur[d4.z >> BUK_SHIFT], 1);
        pairs[p2] = (unsigned int)s4.z | ((unsigned int)(d4.z & 511) << 23);
        int p3 = atomicAdd(&cur[d4.w >> BUK_SHIFT], 1);
        pairs[p3] = (unsigned int)s4.w | ((unsigned int)(d4.w & 511) << 23);
    }
    if (c == 0 && threadIdx.x == 0) {  // scalar tail
        for (int i = V4 << 2; i < E; ++i) {
            int d = dst[i];
            int pos = atomicAdd(&cur[d >> BUK_SHIFT], 1);
            pairs[pos] = (unsigned int)src[i] | ((unsigned int)(d & 511) << 23);
        }
    }
}

// --- pass C: per-bucket counting sort + CSR metadata -----------------------
__global__ __launch_bounds__(256) void k_bucketC(const unsigned int* __restrict__ pairs,
                                                 const int* __restrict__ histT,
                                                 const int* __restrict__ scanI,
                                                 const int* __restrict__ partials,
                                                 int* __restrict__ srt,
                                                 int* __restrict__ counts,
                                                 int* __restrict__ rowoff,
                                                 float* __restrict__ dinv,
                                                 int E, int nbuk, int N) {
    const int b = blockIdx.x;
    const int tid = threadIdx.x;
    __shared__ int h[512];
    __shared__ int loff[512];
    __shared__ int s2[256];

    int idx0 = b * NB_BIN;
    int base = scanI[idx0] - histT[idx0] + partials[idx0 >> 8];
    int end;
    if (b + 1 < nbuk) {
        int idx1 = (b + 1) * NB_BIN;
        end = scanI[idx1] - histT[idx1] + partials[idx1 >> 8];
    } else {
        end = E;
    }

    const int n0 = b << BUK_SHIFT;
    const int nn = min(512, N - n0);

    h[tid] = 0; h[tid + 256] = 0;
    __syncthreads();
    for (int i = base + tid; i < end; i += 256)
        atomicAdd(&h[pairs[i] >> 23], 1);
    __syncthreads();

    int a0 = h[2 * tid], a1 = h[2 * tid + 1];
    s2[tid] = a0 + a1;
    __syncthreads();
    for (int off = 1; off < 256; off <<= 1) {
        int t = (tid >= off) ? s2[tid - off] : 0;
        __syncthreads();
        s2[tid] += t;
        __syncthreads();
    }
    int e2 = s2[tid] - (a0 + a1);
    loff[2 * tid] = e2;
    loff[2 * tid + 1] = e2 + a0;
    __syncthreads();

    for (int i = tid; i < nn; i += 256) {
        int cc = h[i];
        counts[n0 + i] = cc;
        rowoff[n0 + i] = base + loff[i];
        dinv[n0 + i] = rsqrtf((float)cc + 1.0f);
    }
    __syncthreads();
    h[tid] = loff[tid]; h[tid + 256] = loff[tid + 256];
    __syncthreads();
    for (int i = base + tid; i < end; i += 256) {
        unsigned int p = pairs[i];
        int pos = atomicAdd(&h[p >> 23], 1);
        srt[base + pos] = (int)(p & 0x7FFFFFu);
    }
}

// --- register-blocked tiled GEMM: H[N,OUT] = X[N,IN] @ W[IN,OUT] -----------
// BR: fuse relu(out+bias). OB: output bf16 pre-scaled by scale[row].
// IB: input is bf16 (staged to f32 in LDS).
template <int IN, int OUT, int TN, bool BR, bool OB, bool IB>
__global__ __launch_bounds__(256) void k_gemm_tile(const void* __restrict__ Xv,
                                                   const float* __restrict__ W,
                                                   const float* __restrict__ bias,
                                                   const float* __restrict__ scale,
                                                   void* __restrict__ Hv, int N) {
    constexpr int ROWS = 64;
    constexpr int CT = OUT / TN;
    constexpr int RT = 256 / CT;
    constexpr int TM = ROWS / RT;
    static_assert(CT * RT == 256 && TM * RT == ROWS, "tile mismatch");
    __shared__ float Xs[ROWS][IN];
    __shared__ float Ws[IN][OUT];

    const int tid = threadIdx.x;
    const int row0 = blockIdx.x * ROWS;

    for (int i = tid; i < IN * OUT / 4; i += 256)
        ((float4*)Ws)[i] = ((const float4*)W)[i];
    for (int i = tid; i < ROWS * IN / 4; i += 256) {
        int r = i / (IN / 4), kq = i % (IN / 4);
        float4 v = make_float4(0.f, 0.f, 0.f, 0.f);
        if (row0 + r < N) {
            if (IB) {
                uint2 u = ((const uint2*)Xv)[(size_t)(row0 + r) * (IN / 4) + kq];
                v = make_float4(bflo(u.x), bfhi(u.x), bflo(u.y), bfhi(u.y));
            } else {
                v = ((const float4*)Xv)[(size_t)(row0 + r) * (IN / 4) + kq];
            }
        }
        *(float4*)&Xs[r][kq * 4] = v;
    }
    __syncthreads();

    const int tx = tid % CT;
    const int ty = tid / CT;

    float acc[TM][TN];
#pragma unroll
    for (int m = 0; m < TM; ++m)
#pragma unroll
        for (int n = 0; n < TN; ++n) acc[m][n] = 0.0f;

#pragma unroll 2
    for (int kq = 0; kq < IN / 4; ++kq) {
        float a[TM][4];
#pragma unroll
        for (int m = 0; m < TM; ++m) {
            float4 t = *(const float4*)&Xs[ty * TM + m][kq * 4];
            a[m][0] = t.x; a[m][1] = t.y; a[m][2] = t.z; a[m][3] = t.w;
        }
#pragma unroll
        for (int j = 0; j < 4; ++j) {
            float b[TN];
#pragma unroll
            for (int n4 = 0; n4 < TN / 4; ++n4) {
                float4 t = *(const float4*)&Ws[kq * 4 + j][tx * TN + n4 * 4];
                b[n4 * 4 + 0] = t.x; b[n4 * 4 + 1] = t.y;
                b[n4 * 4 + 2] = t.z; b[n4 * 4 + 3] = t.w;
            }
#pragma unroll
            for (int m = 0; m < TM; ++m)
#pragma unroll
                for (int n = 0; n < TN; ++n)
                    acc[m][n] = fmaf(a[m][j], b[n], acc[m][n]);
        }
    }

#pragma unroll
    for (int m = 0; m < TM; ++m) {
        int r = row0 + ty * TM + m;
        if (r >= N) continue;
        float sc = OB ? scale[r] : 1.0f;
#pragma unroll
        for (int n4 = 0; n4 < TN / 4; ++n4) {
            float4 o = make_float4(acc[m][n4 * 4 + 0], acc[m][n4 * 4 + 1],
                                   acc[m][n4 * 4 + 2], acc[m][n4 * 4 + 3]);
            if (BR) {
                float4 b4 = *(const float4*)&bias[tx * TN + n4 * 4];
                o.x = fmaxf(o.x + b4.x, 0.0f);
                o.y = fmaxf(o.y + b4.y, 0.0f);
                o.z = fmaxf(o.z + b4.z, 0.0f);
                o.w = fmaxf(o.w + b4.w, 0.0f);
            }
            if (OB) {
                ushort4 o16;
                o16.x = f2bf(o.x * sc); o16.y = f2bf(o.y * sc);
                o16.z = f2bf(o.z * sc); o16.w = f2bf(o.w * sc);
                *(ushort4*)((unsigned short*)Hv + (size_t)r * OUT + tx * TN + n4 * 4) = o16;
            } else {
                *(float4*)((float*)Hv + (size_t)r * OUT + tx * TN + n4 * 4) = o;
            }
        }
    }
}

// --- aggregation v3b: quarter-wave per edge, uint2 (4 bf16) per lane,
// main loop x4 (4 gathers in flight), then x2 stage, then singles.
// acc = dv * (Hs[node] + sum_e Hs[src_e]);  Hs pre-scaled by dinv.
// BR: relu(acc+bias). OB: bf16 out. PS: pre-scale output by dv.
template <bool BR, bool OB, bool PS>
__global__ void k_agg64_v3b(const int* __restrict__ srt, const int* __restrict__ rowoff,
                            const int* __restrict__ counts, const float* __restrict__ dinv,
                            const uint2* __restrict__ Hs, const float* __restrict__ bias,
                            void* __restrict__ Ov, int N) {
    int node = blockIdx.x * (blockDim.x >> 6) + (threadIdx.x >> 6);
    int lane = threadIdx.x & 63;
    int q = lane >> 4, l4 = lane & 15;
    if (node >= N) return;
    float dv = dinv[node];
    const int* sp = srt + rowoff[node];
    int ce = counts[node];

    float a0 = 0.f, a1 = 0.f, a2 = 0.f, a3 = 0.f;
    if (q == 0) {  // self-loop once
        uint2 u = Hs[(size_t)node * 16 + l4];
        a0 = bflo(u.x); a1 = bfhi(u.x); a2 = bflo(u.y); a3 = bfhi(u.y);
    }
    int e = q;
    for (; e + 12 < ce; e += 16) {  // 4 gathers in flight per quarter
        int s0 = sp[e], s1 = sp[e + 4], s2 = sp[e + 8], s3 = sp[e + 12];
        uint2 u0 = Hs[(size_t)s0 * 16 + l4];
        uint2 u1 = Hs[(size_t)s1 * 16 + l4];
        uint2 u2 = Hs[(size_t)s2 * 16 + l4];
        uint2 u3 = Hs[(size_t)s3 * 16 + l4];
        a0 += bflo(u0.x); a1 += bfhi(u0.x); a2 += bflo(u0.y); a3 += bfhi(u0.y);
        a0 += bflo(u1.x); a1 += bfhi(u1.x); a2 += bflo(u1.y); a3 += bfhi(u1.y);
        a0 += bflo(u2.x); a1 += bfhi(u2.x); a2 += bflo(u2.y); a3 += bfhi(u2.y);
        a0 += bflo(u3.x); a1 += bfhi(u3.x); a2 += bflo(u3.y); a3 += bfhi(u3.y);
    }
    if (e + 4 < ce) {  // x2 stage
        int s0 = sp[e], s1 = sp[e + 4];
        uint2 u0 = Hs[(size_t)s0 * 16 + l4];
        uint2 u1 = Hs[(size_t)s1 * 16 + l4];
        a0 += bflo(u0.x); a1 += bfhi(u0.x); a2 += bflo(u0.y); a3 += bfhi(u0.y);
        a0 += bflo(u1.x); a1 += bfhi(u1.x); a2 += bflo(u1.y); a3 += bfhi(u1.y);
        e += 8;
    }
    if (e < ce) {
        uint2 u = Hs[(size_t)sp[e] * 16 + l4];
        a0 += bflo(u.x); a1 += bfhi(u.x); a2 += bflo(u.y); a3 += bfhi(u.y);
    }
    a0 += __shfl_xor(a0, 16, 64); a0 += __shfl_xor(a0, 32, 64);
    a1 += __shfl_xor(a1, 16, 64); a1 += __shfl_xor(a1, 32, 64);
    a2 += __shfl_xor(a2, 16, 64); a2 += __shfl_xor(a2, 32, 64);
    a3 += __shfl_xor(a3, 16, 64); a3 += __shfl_xor(a3, 32, 64);

    float o0 = a0 * dv, o1 = a1 * dv, o2 = a2 * dv, o3 = a3 * dv;
    if (BR) {
        float4 b4 = *(const float4*)(bias + 4 * l4);
        o0 = fmaxf(o0 + b4.x, 0.0f);
        o1 = fmaxf(o1 + b4.y, 0.0f);
        o2 = fmaxf(o2 + b4.z, 0.0f);
        o3 = fmaxf(o3 + b4.w, 0.0f);
    }
    if (PS) { o0 *= dv; o1 *= dv; o2 *= dv; o3 *= dv; }
    if (q == 0) {
        if (OB) {
            uint2 o;
            o.x = (unsigned int)f2bf(o0) | ((unsigned int)f2bf(o1) << 16);
            o.y = (unsigned int)f2bf(o2) | ((unsigned int)f2bf(o3) << 16);
            ((uint2*)Ov)[(size_t)node * 16 + l4] = o;
        } else {
            ((float4*)Ov)[(size_t)node * 16 + l4] = make_float4(o0, o1, o2, o3);
        }
    }
}

// --- pooling (batch sorted): wave-run accumulation ------------------------
__global__ void k_zero_f(float* p, int n) {
    int i = blockIdx.x * blockDim.x + threadIdx.x;
    if (i < n) p[i] = 0.0f;
}

__global__ void k_pool_seg(const float* __restrict__ H, const int* __restrict__ batch,
                           float* __restrict__ sums, float* __restrict__ cnt, int N) {
    int gw = (blockIdx.x * blockDim.x + threadIdx.x) >> 6;
    int lane = threadIdx.x & 63;
    int start = gw * 64;
    if (start >= N) return;
    int end = min(N, start + 64);
    int gcur = batch[start];
    float acc = 0.0f, c = 0.0f;
    for (int i = start; i < end; ++i) {
        int g = batch[i];
        if (g != gcur) {
            atomicAdd(&sums[(size_t)gcur * 64 + lane], acc);
            if (lane == 0) atomicAdd(&cnt[gcur], c);
            acc = 0.0f; c = 0.0f; gcur = g;
        }
        acc += H[(size_t)i * 64 + lane];
        c += 1.0f;
    }
    atomicAdd(&sums[(size_t)gcur * 64 + lane], acc);
    if (lane == 0) atomicAdd(&cnt[gcur], c);
}

// --- head: mean, fc, log_softmax ------------------------------------------
__global__ void k_head(const float* __restrict__ sums, const float* __restrict__ cnt,
                       const float* __restrict__ fcw, const float* __restrict__ fcb,
                       float* __restrict__ out, int G) {
    int g = blockIdx.x * blockDim.x + threadIdx.x;
    if (g >= G) return;
    float inv = 1.0f / fmaxf(cnt[g], 1.0f);
    float l[6];
#pragma unroll
    for (int c = 0; c < 6; ++c) {
        float acc = fcb[c];
        for (int f = 0; f < 64; ++f)
            acc = fmaf(sums[(size_t)g * 64 + f] * inv, fcw[f * 6 + c], acc);
        l[c] = acc;
    }
    float m = l[0];
#pragma unroll
    for (int c = 1; c < 6; ++c) m = fmaxf(m, l[c]);
    float se = 0.0f;
#pragma unroll
    for (int c = 0; c < 6; ++c) se += expf(l[c] - m);
    float lse = m + logf(se);
#pragma unroll
    for (int c = 0; c < 6; ++c) out[(size_t)g * 6 + c] = l[c] - lse;
}

// ---------------------------------------------------------------------------
extern "C" void kernel_launch(void* const* d_in, const int* in_sizes, int n_in,
                              void* d_out, int out_size, void* d_ws, size_t ws_size,
                              hipStream_t stream) {
    const float* x    = (const float*)d_in[0];
    const int*   eidx = (const int*)d_in[1];
    const int*   batch= (const int*)d_in[2];
    const float* W1   = (const float*)d_in[3];
    const float* b1   = (const float*)d_in[4];
    const float* W2   = (const float*)d_in[5];
    const float* b2   = (const float*)d_in[6];
    const float* W3   = (const float*)d_in[7];
    const float* b3   = (const float*)d_in[8];
    const float* fcw  = (const float*)d_in[9];
    const float* fcb  = (const float*)d_in[10];
    float* out = (float*)d_out;

    const int N = in_sizes[2];          // 100000
    const int E = in_sizes[1] / 2;      // 3200000
    const int G = out_size / 6;         // 512
    const int nbuk = (N + 511) >> BUK_SHIFT;  // 196
    const int M = nbuk * NB_BIN;              // 100352

    const int* src = eidx;
    const int* dst = eidx + E;

    float* ws = (float*)d_ws;
    size_t off = 0;
    auto take = [&](size_t n4) {
        float* p = ws + off;
        off += (n4 + 15) & ~(size_t)15;
        return p;
    };
    float* dinv    = take((size_t)N);
    int*   srt     = (int*)take((size_t)E);
    int*   rowoff  = (int*)take((size_t)N);
    int*   counts  = (int*)take((size_t)N);
    int*   histT   = (int*)take((size_t)M);
    int*   scanI   = (int*)take((size_t)M);
    int*   partials= (int*)take(512);
    uint2* H16a    = (uint2*)take((size_t)N * 32);  // N*64 bf16
    uint2* H16b    = (uint2*)take((size_t)N * 32);  // N*64 bf16
    float* A32     = take((size_t)N * 64);
    float* B32     = take((size_t)N * 128);
    float* sums    = take((size_t)G * 64);
    float* cnt     = take((size_t)G);
    (void)ws_size;

    unsigned int* pairs = (unsigned int*)B32;  // alias: B32 dead until GEMM2

    const int B = 256;
    const int NBLK_M = grid_for(M, 256);  // 392

    // --- CSR build (LDS-binned two-level radix, packed pairs, int4 reads) ---
    k_histA<<<NB_BIN, B, 0, stream>>>(dst, histT, E, nbuk);
    k_scan_block_lin<<<NBLK_M, B, 0, stream>>>(histT, scanI, partials, M);
    k_scan_partials<<<1, 512, 0, stream>>>(partials, NBLK_M);
    k_binB<<<NB_BIN, B, 0, stream>>>(src, dst, histT, scanI, partials, pairs, E, nbuk);
    k_bucketC<<<nbuk, B, 0, stream>>>(pairs, histT, scanI, partials, srt, counts,
                                      rowoff, dinv, E, nbuk, N);

    // --- layer 1: H16a = (x@W1)*dinv (bf16); agg -> H16b (bf16, rescaled) ---
    k_gemm_tile<128, 64, 4, false, true, false><<<grid_for(N, 64), B, 0, stream>>>(x, W1, nullptr, dinv, H16a, N);
    k_agg64_v3b<true, true, true><<<grid_for(N, 4), B, 0, stream>>>(srt, rowoff, counts, dinv, H16a, b1, H16b, N);

    // --- layer 2 (aggregate-first): H16a = A_norm-apply on H16b (bf16 out);
    //     B32 = relu(H16a@W2 + b2) [N,128] (bf16-input GEMM) ---
    k_agg64_v3b<false, true, false><<<grid_for(N, 4), B, 0, stream>>>(srt, rowoff, counts, dinv, H16b, nullptr, H16a, N);
    k_gemm_tile<64, 128, 8, true, false, true><<<grid_for(N, 64), B, 0, stream>>>(H16a, W2, b2, nullptr, B32, N);

    // --- layer 3: H16a = (B32@W3)*dinv (bf16); agg -> A32 = relu(.+b3) fp32 ---
    k_gemm_tile<128, 64, 4, false, true, false><<<grid_for(N, 64), B, 0, stream>>>(B32, W3, nullptr, dinv, H16a, N);
    k_agg64_v3b<true, false, false><<<grid_for(N, 4), B, 0, stream>>>(srt, rowoff, counts, dinv, H16a, b3, A32, N);

    // --- pool + head ---
    k_zero_f<<<grid_for(G * 64, B), B, 0, stream>>>(sums, G * 64);
    k_zero_f<<<grid_for(G, B), B, 0, stream>>>(cnt, G);
    k_pool_seg<<<grid_for((long long)grid_for(N, 64) * 64, B), B, 0, stream>>>(A32, batch, sums, cnt, N);
    k_head<<<grid_for(G, 64), 64, 0, stream>>>(sums, cnt, fcw, fcb, out, G);
}